// Round 5
// baseline (218.673 us; speedup 1.0000x reference)
//
#include <hip/hip_runtime.h>

// Fused loss: 0.2 * mean(dx^2 - dy^2) + 0.8 * masked-MSE(target>0)
// dx = Sv(vert) then D(horiz) on e = pred - target; dy = D(vert) then Sv(horiz)
//   Sv = [0.25, 1, 1.5, 1, 0.25], D = [-0.25, -0.5, 0, 0.5, 0.25]
// reflect-101 halo of 2 (exact; absmax 0.0 in R1-R4).
//
// R5: barrier-free, LDS-free. Each WAVE owns 2 output rows x 256 cols.
// All 24 float4 loads (6 rows x {pred,target}) + masked halo scalars are
// issued up-front behind one sched_barrier(0) (prevents the R2/R3 allocator
// re-serialization), then consumed. Horizontal neighbors via __shfl; lanes
// 0/63 substitute halo-column values (R2-verified logic). No __shared__,
// no __syncthreads: waves free-run, VMEM/VALU overlap across 16 waves/CU.

__device__ __forceinline__ int reflect101(int i, int n) {
    if (i < 0) i = -i;
    if (i >= n) i = 2 * n - 2 - i;
    return i;
}

__global__ __launch_bounds__(256, 4) void loss_main(
    const float* __restrict__ pred, const float* __restrict__ target,
    double* __restrict__ acc, int H, int W, int slotMask)
{
    const int tid  = threadIdx.x;
    const int lane = tid & 63;
    const int wv   = tid >> 6;
    const int cs   = blockIdx.y * 256;           // column segment start
    const int r    = blockIdx.x * 8 + wv * 2;    // first owned row
    const int c    = cs + lane * 4;

    const bool isL = (lane == 0);
    const bool isR = (lane == 63);
    const bool hload = isL || isR;
    int hcol = 0; bool hswap = false;
    if (isL) { hswap = (cs == 0);       hcol = hswap ? 1       : cs - 2;   }
    if (isR) { hswap = (cs + 256 == W); hcol = hswap ? (W - 3) : cs + 256; }

    float4 p0, p1, p2, p3, p4, p5, t0, t1, t2, t3, t4, t5;
    float2 hp0, hp1, hp2, hp3, hp4, hp5, ht0, ht1, ht2, ht3, ht4, ht5;
    hp0 = hp1 = hp2 = hp3 = hp4 = hp5 = make_float2(0.f, 0.f);
    ht0 = ht1 = ht2 = ht3 = ht4 = ht5 = make_float2(0.f, 0.f);

#define LOADROW(j, lr)                                                  \
    {                                                                   \
        const int gr = reflect101((lr), H);                             \
        const float* pr = pred   + (size_t)gr * W;                      \
        const float* tr = target + (size_t)gr * W;                      \
        p##j = *(const float4*)(pr + c);                                \
        t##j = *(const float4*)(tr + c);                                \
        if (hload) {                                                    \
            hp##j = make_float2(pr[hcol], pr[hcol + 1]);                \
            ht##j = make_float2(tr[hcol], tr[hcol + 1]);                \
        }                                                               \
    }

    LOADROW(0, r - 2)
    LOADROW(1, r - 1)
    LOADROW(2, r)
    LOADROW(3, r + 1)
    LOADROW(4, r + 2)
    LOADROW(5, r + 3)
#undef LOADROW

    // Fence: all 24+24 loads issued before any consumption can be scheduled.
    __builtin_amdgcn_sched_barrier(0);

#define SUB4(a, b) make_float4(a.x - b.x, a.y - b.y, a.z - b.z, a.w - b.w)
    const float4 e0 = SUB4(p0, t0);
    const float4 e1 = SUB4(p1, t1);
    const float4 e2 = SUB4(p2, t2);
    const float4 e3 = SUB4(p3, t3);
    const float4 e4 = SUB4(p4, t4);
    const float4 e5 = SUB4(p5, t5);
#undef SUB4
#define HSUB(j) (hswap ? make_float2(hp##j.y - ht##j.y, hp##j.x - ht##j.x) \
                       : make_float2(hp##j.x - ht##j.x, hp##j.y - ht##j.y))
    const float2 h0 = HSUB(0);
    const float2 h1 = HSUB(1);
    const float2 h2 = HSUB(2);
    const float2 h3 = HSUB(3);
    const float2 h4 = HSUB(4);
    const float2 h5 = HSUB(5);
#undef HSUB

    float mse = 0.f, cnt = 0.f, g = 0.f;

    // masked MSE on the two owned rows (window rows 2,3)
    if (t2.x > 0.f) { mse += e2.x * e2.x; cnt += 1.f; }
    if (t2.y > 0.f) { mse += e2.y * e2.y; cnt += 1.f; }
    if (t2.z > 0.f) { mse += e2.z * e2.z; cnt += 1.f; }
    if (t2.w > 0.f) { mse += e2.w * e2.w; cnt += 1.f; }
    if (t3.x > 0.f) { mse += e3.x * e3.x; cnt += 1.f; }
    if (t3.y > 0.f) { mse += e3.y * e3.y; cnt += 1.f; }
    if (t3.z > 0.f) { mse += e3.z * e3.z; cnt += 1.f; }
    if (t3.w > 0.f) { mse += e3.w * e3.w; cnt += 1.f; }

    auto crow = [&](const float4& E0, const float4& E1, const float4& E2,
                    const float4& E3, const float4& E4,
                    const float2& H0, const float2& H1, const float2& H2,
                    const float2& H3, const float2& H4) {
        float4 sv, dv;
        sv.x = 0.25f*(E0.x + E4.x) + (E1.x + E3.x) + 1.5f*E2.x;
        sv.y = 0.25f*(E0.y + E4.y) + (E1.y + E3.y) + 1.5f*E2.y;
        sv.z = 0.25f*(E0.z + E4.z) + (E1.z + E3.z) + 1.5f*E2.z;
        sv.w = 0.25f*(E0.w + E4.w) + (E1.w + E3.w) + 1.5f*E2.w;
        dv.x = 0.25f*(E4.x - E0.x) + 0.5f*(E3.x - E1.x);
        dv.y = 0.25f*(E4.y - E0.y) + 0.5f*(E3.y - E1.y);
        dv.z = 0.25f*(E4.z - E0.z) + 0.5f*(E3.z - E1.z);
        dv.w = 0.25f*(E4.w - E0.w) + 0.5f*(E3.w - E1.w);

        const float svhx = 0.25f*(H0.x + H4.x) + (H1.x + H3.x) + 1.5f*H2.x;
        const float svhy = 0.25f*(H0.y + H4.y) + (H1.y + H3.y) + 1.5f*H2.y;
        const float dvhx = 0.25f*(H4.x - H0.x) + 0.5f*(H3.x - H1.x);
        const float dvhy = 0.25f*(H4.y - H0.y) + 0.5f*(H3.y - H1.y);

        float sv_m2 = __shfl_up(sv.z, 1, 64);
        float sv_m1 = __shfl_up(sv.w, 1, 64);
        float sv_p4 = __shfl_down(sv.x, 1, 64);
        float sv_p5 = __shfl_down(sv.y, 1, 64);
        float dv_m2 = __shfl_up(dv.z, 1, 64);
        float dv_m1 = __shfl_up(dv.w, 1, 64);
        float dv_p4 = __shfl_down(dv.x, 1, 64);
        float dv_p5 = __shfl_down(dv.y, 1, 64);
        if (isL) { sv_m2 = svhx; sv_m1 = svhy; dv_m2 = dvhx; dv_m1 = dvhy; }
        if (isR) { sv_p4 = svhx; sv_p5 = svhy; dv_p4 = dvhx; dv_p5 = dvhy; }

        const float dx0 = 0.25f*(sv.z - sv_m2) + 0.5f*(sv.y - sv_m1);
        const float dx1 = 0.25f*(sv.w - sv_m1) + 0.5f*(sv.z - sv.x);
        const float dx2 = 0.25f*(sv_p4 - sv.x) + 0.5f*(sv.w - sv.y);
        const float dx3 = 0.25f*(sv_p5 - sv.y) + 0.5f*(sv_p4 - sv.z);
        const float dy0 = 0.25f*(dv_m2 + dv.z) + (dv_m1 + dv.y) + 1.5f*dv.x;
        const float dy1 = 0.25f*(dv_m1 + dv.w) + (dv.x + dv.z) + 1.5f*dv.y;
        const float dy2 = 0.25f*(dv.x + dv_p4) + (dv.y + dv.w) + 1.5f*dv.z;
        const float dy3 = 0.25f*(dv.y + dv_p5) + (dv.z + dv_p4) + 1.5f*dv.w;

        g += (dx0*dx0 - dy0*dy0) + (dx1*dx1 - dy1*dy1)
           + (dx2*dx2 - dy2*dy2) + (dx3*dx3 - dy3*dy3);
    };

    crow(e0, e1, e2, e3, e4, h0, h1, h2, h3, h4);   // output row r
    crow(e1, e2, e3, e4, e5, h1, h2, h3, h4, h5);   // output row r+1

    // ---- per-wave reduction -> striped double atomics (no LDS, no barrier)
    for (int off = 32; off > 0; off >>= 1) {
        mse += __shfl_down(mse, off, 64);
        cnt += __shfl_down(cnt, off, 64);
        g   += __shfl_down(g,   off, 64);
    }
    if (lane == 0) {
        double* a = acc + 3 * (blockIdx.x & slotMask);
        atomicAdd(&a[0], (double)mse);
        atomicAdd(&a[1], (double)cnt);
        atomicAdd(&a[2], (double)g);
    }
}

__global__ void loss_final(const double* __restrict__ acc,
                           float* __restrict__ out, double inv_hw, int slots)
{
    double m = 0.0, c = 0.0, g = 0.0;
    for (int s = threadIdx.x; s < slots; s += 64) {
        m += acc[3 * s];
        c += acc[3 * s + 1];
        g += acc[3 * s + 2];
    }
    for (int off = 32; off > 0; off >>= 1) {
        m += __shfl_down(m, off, 64);
        c += __shfl_down(c, off, 64);
        g += __shfl_down(g, off, 64);
    }
    if (threadIdx.x == 0) {
        double cnt = c < 1.0 ? 1.0 : c;
        out[0] = (float)(0.2 * (g * inv_hw) + 0.8 * (m / cnt));
    }
}

extern "C" void kernel_launch(void* const* d_in, const int* in_sizes, int n_in,
                              void* d_out, int out_size, void* d_ws, size_t ws_size,
                              hipStream_t stream) {
    const float* pred   = (const float*)d_in[0];
    const float* target = (const float*)d_in[1];
    float* out  = (float*)d_out;
    double* acc = (double*)d_ws;

    const int H = 4096, W = 4096;
    const int slots = (ws_size >= (size_t)(64 * 3 * sizeof(double))) ? 64 : 1;

    hipMemsetAsync(acc, 0, slots * 3 * sizeof(double), stream);

    dim3 grid(H / 8, W / 256);   // (512, 16): x fastest -> vertical L2 locality
    loss_main<<<grid, 256, 0, stream>>>(pred, target, acc, H, W, slots - 1);
    loss_final<<<1, 64, 0, stream>>>(acc, out, 1.0 / ((double)H * (double)W), slots);
}

// Round 6
// 147.501 us; speedup vs baseline: 1.4825x; 1.4825x over previous
//
#include <hip/hip_runtime.h>

// Fused loss: 0.2 * mean(dx^2 - dy^2) + 0.8 * masked-MSE(target>0)
// dx = Sv(vert) ∘ D(horiz) on e = pred - target;  dy = D(vert) ∘ Sv(horiz)
//   Sv = [0.25, 1, 1.5, 1, 0.25], D = [-0.25, -0.5, 0, 0.5, 0.25]
// reflect-101 halo of 2 on e (exact; absmax 0.0 in R1-R5).
//
// R6 = R4 (async global_load_lds staging, verified) with ONE change:
// the per-block reduction result goes to a PRIVATE workspace slot via plain
// stores instead of 3 same-cache-line f64 atomicAdds. R1/R3/R4 durations
// reconstruct as Nblocks*3*15.2ns of serialized line-RMWs (183/93/93 us) --
// the atomic queue, not the memory system, was the binding constraint.
// loss_final reduces the 2048*3 doubles (48 KB, L2-resident).

#define TW 256
#define TH 32
#define LROWS 36   // TH + 4
#define LW 264     // row stride (words): interior cols 4..259, halo 2,3,260,261

__device__ __forceinline__ int reflect101(int i, int n) {
    if (i < 0) i = -i;
    if (i >= n) i = 2 * n - 2 - i;
    return i;
}

__device__ __forceinline__ void async16(const float* g, float* l) {
    __builtin_amdgcn_global_load_lds(
        (const __attribute__((address_space(1))) void*)g,
        (__attribute__((address_space(3))) void*)l,
        16, 0, 0);
}

__global__ __launch_bounds__(256) void loss_main(
    const float* __restrict__ pred, const float* __restrict__ target,
    double* __restrict__ part, int H, int W)
{
    __shared__ float psh[LROWS][LW];
    __shared__ float tsh[LROWS][LW];
    __shared__ float partials[4][3];

    const int tid  = threadIdx.x;
    const int lane = tid & 63;
    const int w    = tid >> 6;
    const int r0 = blockIdx.y * TH;
    const int c0 = blockIdx.x * TW;

    // ---- phase A: async global->LDS, 18 row-segments per wave, all in flight
#pragma unroll
    for (int j = 0; j < 18; ++j) {
        const int idx = j * 4 + w;
        const int row = (j >= 9) ? idx - 36 : idx;
        const int gr  = reflect101(r0 - 2 + row, H);
        const size_t goff = (size_t)gr * W + c0 + lane * 4;
        if (j >= 9) async16(target + goff, &tsh[row][4]);
        else        async16(pred   + goff, &psh[row][4]);
    }

    // ---- halo columns: 144 threads, 1 (row, halo-col) pair each, both tensors
    if (tid < 144) {
        const int row = tid >> 2;
        const int hc  = tid & 3;
        const int lc  = (hc < 2) ? (2 + hc) : (258 + hc);   // 2,3,260,261
        const int gc  = reflect101((hc < 2) ? (c0 - 2 + hc)
                                            : (c0 + 254 + hc), W);
        const int gr  = reflect101(r0 - 2 + row, H);
        const size_t off = (size_t)gr * W + gc;
        psh[row][lc] = pred[off];
        tsh[row][lc] = target[off];
    }
    __syncthreads();   // drains vmcnt(0): async DMA + halo ds_writes complete

    // ---- phase B: separable conv + masked MSE, rolling 5-row window ----
    const int cg = lane;            // output LDS cols 4+4cg .. 7+4cg
    const int rb = w * 8;           // window rows rb .. rb+11
    float mse = 0.f, cnt = 0.f, g = 0.f;

    float4 D0, D1, D2, D3, D4, S0, S1, S2, S3, S4;

    auto hpass = [&](int rw, bool doMse, float4& D_, float4& S_) {
        const float4 p0 = *(const float4*)&psh[rw][4 * cg];
        const float4 p1 = *(const float4*)&psh[rw][4 * cg + 4];
        const float4 p2 = *(const float4*)&psh[rw][4 * cg + 8];
        const float4 t0 = *(const float4*)&tsh[rw][4 * cg];
        const float4 t1 = *(const float4*)&tsh[rw][4 * cg + 4];
        const float4 t2 = *(const float4*)&tsh[rw][4 * cg + 8];
        const float e0z = p0.z - t0.z, e0w = p0.w - t0.w;
        const float e1x = p1.x - t1.x, e1y = p1.y - t1.y;
        const float e1z = p1.z - t1.z, e1w = p1.w - t1.w;
        const float e2x = p2.x - t2.x, e2y = p2.y - t2.y;
        D_.x = 0.25f * (e1z - e0z) + 0.5f * (e1y - e0w);
        D_.y = 0.25f * (e1w - e0w) + 0.5f * (e1z - e1x);
        D_.z = 0.25f * (e2x - e1x) + 0.5f * (e1w - e1y);
        D_.w = 0.25f * (e2y - e1y) + 0.5f * (e2x - e1z);
        S_.x = 0.25f * (e0z + e1z) + (e0w + e1y) + 1.5f * e1x;
        S_.y = 0.25f * (e0w + e1w) + (e1x + e1z) + 1.5f * e1y;
        S_.z = 0.25f * (e1x + e2x) + (e1y + e1w) + 1.5f * e1z;
        S_.w = 0.25f * (e1y + e2y) + (e1z + e2x) + 1.5f * e1w;
        if (doMse) {
            if (t1.x > 0.f) { mse += e1x * e1x; cnt += 1.f; }
            if (t1.y > 0.f) { mse += e1y * e1y; cnt += 1.f; }
            if (t1.z > 0.f) { mse += e1z * e1z; cnt += 1.f; }
            if (t1.w > 0.f) { mse += e1w * e1w; cnt += 1.f; }
        }
    };

    hpass(rb + 0, false, D0, S0);
    hpass(rb + 1, false, D1, S1);
    hpass(rb + 2, true,  D2, S2);
    hpass(rb + 3, true,  D3, S3);

#pragma unroll
    for (int k = 0; k < 8; ++k) {
        hpass(rb + 4 + k, (k < 6), D4, S4);
        const float dx0 = 0.25f * (D0.x + D4.x) + (D1.x + D3.x) + 1.5f * D2.x;
        const float dx1 = 0.25f * (D0.y + D4.y) + (D1.y + D3.y) + 1.5f * D2.y;
        const float dx2 = 0.25f * (D0.z + D4.z) + (D1.z + D3.z) + 1.5f * D2.z;
        const float dx3 = 0.25f * (D0.w + D4.w) + (D1.w + D3.w) + 1.5f * D2.w;
        const float dy0 = 0.25f * (S4.x - S0.x) + 0.5f * (S3.x - S1.x);
        const float dy1 = 0.25f * (S4.y - S0.y) + 0.5f * (S3.y - S1.y);
        const float dy2 = 0.25f * (S4.z - S0.z) + 0.5f * (S3.z - S1.z);
        const float dy3 = 0.25f * (S4.w - S0.w) + 0.5f * (S3.w - S1.w);
        g += (dx0 * dx0 - dy0 * dy0) + (dx1 * dx1 - dy1 * dy1)
           + (dx2 * dx2 - dy2 * dy2) + (dx3 * dx3 - dy3 * dy3);
        D0 = D1; D1 = D2; D2 = D3; D3 = D4;
        S0 = S1; S1 = S2; S2 = S3; S3 = S4;
    }

    // ---- reduction: wave shuffle -> LDS partials -> PLAIN STORES (no atomics)
    for (int off = 32; off > 0; off >>= 1) {
        mse += __shfl_down(mse, off, 64);
        cnt += __shfl_down(cnt, off, 64);
        g   += __shfl_down(g,   off, 64);
    }
    if (lane == 0) {
        partials[w][0] = mse;
        partials[w][1] = cnt;
        partials[w][2] = g;
    }
    __syncthreads();
    if (tid == 0) {
        float m = 0.f, c2 = 0.f, gg = 0.f;
        for (int wv = 0; wv < 4; ++wv) {
            m  += partials[wv][0];
            c2 += partials[wv][1];
            gg += partials[wv][2];
        }
        const int bid = blockIdx.y * gridDim.x + blockIdx.x;
        double* slot = part + 3 * bid;
        slot[0] = (double)m;
        slot[1] = (double)c2;
        slot[2] = (double)gg;
    }
}

__global__ __launch_bounds__(256) void loss_final(
    const double* __restrict__ part, int nslots,
    float* __restrict__ out, double inv_hw)
{
    __shared__ double red[4][3];
    double m = 0.0, c = 0.0, g = 0.0;
    for (int s = threadIdx.x; s < nslots; s += 256) {
        m += part[3 * s];
        c += part[3 * s + 1];
        g += part[3 * s + 2];
    }
    for (int off = 32; off > 0; off >>= 1) {
        m += __shfl_down(m, off, 64);
        c += __shfl_down(c, off, 64);
        g += __shfl_down(g, off, 64);
    }
    const int w = threadIdx.x >> 6;
    if ((threadIdx.x & 63) == 0) { red[w][0] = m; red[w][1] = c; red[w][2] = g; }
    __syncthreads();
    if (threadIdx.x == 0) {
        m = red[0][0] + red[1][0] + red[2][0] + red[3][0];
        c = red[0][1] + red[1][1] + red[2][1] + red[3][1];
        g = red[0][2] + red[1][2] + red[2][2] + red[3][2];
        const double cnt = c < 1.0 ? 1.0 : c;
        out[0] = (float)(0.2 * (g * inv_hw) + 0.8 * (m / cnt));
    }
}

extern "C" void kernel_launch(void* const* d_in, const int* in_sizes, int n_in,
                              void* d_out, int out_size, void* d_ws, size_t ws_size,
                              hipStream_t stream) {
    const float* pred   = (const float*)d_in[0];
    const float* target = (const float*)d_in[1];
    float* out   = (float*)d_out;
    double* part = (double*)d_ws;

    const int H = 4096, W = 4096;
    const int nblocks = (W / TW) * (H / TH);   // 2048; 48 KB of ws

    dim3 grid(W / TW, H / TH);   // (16, 128) = 2048 blocks
    loss_main<<<grid, 256, 0, stream>>>(pred, target, part, H, W);
    loss_final<<<1, 256, 0, stream>>>(part, nblocks, out,
                                      1.0 / ((double)H * (double)W));
}